// Round 3
// baseline (1332.697 us; speedup 1.0000x reference)
//
#include <hip/hip_runtime.h>

#define WIDTH   1024
#define HALF_W  512
#define DEPTH   8
#define BDEPTH  10
#define BATCH   65536
#define ROWS    16          // batch rows per block

typedef _Float16 v8h __attribute__((ext_vector_type(8)));   // MFMA A/B frag (4 VGPR)
typedef _Float16 v4h __attribute__((ext_vector_type(4)));   // packed 4 x fp16 (8 B)
typedef float    v4f __attribute__((ext_vector_type(4)));   // MFMA C/D frag

static __device__ __forceinline__ unsigned short f2h(float x) {
    _Float16 h = (_Float16)x;                 // RNE, rel err <= 2^-11
    return __builtin_bit_cast(unsigned short, h);
}

// ---------------------------------------------------------------------------
// LDS layout: 32 slices x 16 rows x 32 fp16, slice stride 1024 B (32 KB total).
// Swizzle: byte ^= (((r>>1) ^ slice) & 7) << 4.
//   Bijective: XOR touches bits [6:4]; key depends on r>>1 (addr bits >=7)
//   and slice (bits >=10), both invariant under the XOR.
//   Conflict audit at quarter-wave granularity (16 lanes):
//     A-read  b128 (r=lw, k=q*8):  slot=((lw&1)<<2|q)^(lw>>1) -> 2 lanes/slot
//     T-write b64  (slice=nt*16+lw): slot=const^(lw&7)        -> 2 lanes/2banks
//     init   b128  (slice=g):        slot=const^(g&7)         -> 2 lanes/slot
//   All <=2-way: free (m136).
// ---------------------------------------------------------------------------
static __device__ __forceinline__ int xoff(int slice, int r, int k) {
    int b = (slice << 10) + (r << 6) + (k << 1);
    return b ^ ((((r >> 1) ^ slice) & 7) << 4);
}

// ---------------------------------------------------------------------------
// Setup: compose 5 butterfly steps into 32x32 matrices, write in B-frag order.
// ---------------------------------------------------------------------------
__global__ void gen_mats(const float* __restrict__ bp, unsigned short* __restrict__ mats)
{
    const int bid = blockIdx.x;
    const int grp = bid & 31;
    const int ph  = (bid >> 5) & 1;
    const int L   = bid >> 6;
    const int tid = threadIdx.x;

    __shared__ float M[2][32][32];

    for (int i = tid; i < 1024; i += 64)
        M[0][i >> 5][i & 31] = ((i >> 5) == (i & 31)) ? 1.0f : 0.0f;
    __syncthreads();

    int buf = 0;
    for (int s = 0; s < 5; ++s) {
        const int t = ph * 5 + s;
        const int stride = 1 << (4 - s);
        for (int idx = tid; idx < 512; idx += 64) {
            const int a  = idx >> 5;
            const int c  = idx & 31;
            const int lo = ((a & ~(stride - 1)) << 1) | (a & (stride - 1));
            const int hi = lo | stride;
            const int p_low = (ph == 0) ? ((lo << 5) | grp) : ((grp << 5) | lo);
            const int j = (((p_low << t) | (p_low >> (10 - t))) & 1023) & 511;
            const float theta = bp[L * (HALF_W * BDEPTH) + j * BDEPTH + t];
            float sn, cs;
            sincosf(theta, &sn, &cs);
            const float xl = M[buf][lo][c];
            const float xh = M[buf][hi][c];
            M[1 - buf][lo][c] =  cs * xl + sn * xh;
            M[1 - buf][hi][c] = -sn * xl + cs * xh;
        }
        buf = 1 - buf;
        __syncthreads();
    }

    unsigned short* out = mats + (size_t)bid * 1024;
    for (int i = tid; i < 1024; i += 64) {
        const int nt   = i >> 9;
        const int lane = (i >> 3) & 63;
        const int jj   = i & 7;
        const int n = nt * 16 + (lane & 15);
        const int k = (lane >> 4) * 8 + jj;
        out[i] = f2h(M[buf][n][k]);
    }
}

// ---------------------------------------------------------------------------
// Fuse activation constants: {slope/scale, bias/scale, scale, 0} per (L, p).
// ---------------------------------------------------------------------------
__global__ void fuse_act(const float* __restrict__ bias,
                         const float* __restrict__ slope,
                         const float* __restrict__ scale,
                         float4* __restrict__ actT)
{
    const int i = blockIdx.x * 256 + threadIdx.x;
    if (i < (DEPTH - 1) * WIDTH) {
        const float b = bias[i], s = slope[i], c = scale[i];
        const float r = 1.0f / c;
        actT[i] = make_float4(s * r, b * r, c, 0.0f);
    }
}

// ---------------------------------------------------------------------------
// Main: 16 rows per block, 256 threads (4 waves = 4 slice octets).
// Single 32 KB LDS buffer; phases transpose in place:
//   [stage 8 A-frags -> regs][BAR][MFMA + (act) + transposed write][BAR]
// Residency: 4-wave blocks + 32 KB LDS -> up to 4 independent blocks/CU
// (16 waves). R2 post-mortem: an 8-wave/64 KB block with ~124+eps regs/wave
// rounded to 1 block/CU (23% occ); fine-grained blocks give 3-4 blocks/CU
// even if the per-wave footprint only fits 3/SIMD.
// __launch_bounds__ 2nd arg = min BLOCKS/CU on this toolchain (R1: (512,4)
// forced VGPR=64=512/8waves; CUDA semantics confirmed). (256,4) -> cap 128.
// ---------------------------------------------------------------------------
__global__ void __launch_bounds__(256, 4) butterfly_net(
    const float* __restrict__ X,
    const unsigned short* __restrict__ mats,
    const float4* __restrict__ actT,
    float* __restrict__ out)
{
    __shared__ unsigned char Xb[32 * 1024];   // 32 KB

    const int tid  = threadIdx.x;
    const int lane = tid & 63;
    const int oct  = tid >> 6;        // wave 0..3 = slice octet
    const int lw   = lane & 15;
    const int q    = lane >> 4;
    const int row0 = blockIdx.x * ROWS;

    // ---- initial staging: fp32 global -> fp16 LDS, layout (g, r, h)
    {
        const int g = tid & 31;
        const int m = tid >> 5;                   // 0..7
        #pragma unroll
        for (int it = 0; it < 8; ++it) {
            const int cmb = it * 8 + m;           // 0..63
            const int r   = cmb >> 2;             // 0..15
            const int h0  = (cmb & 3) * 8;        // 0,8,16,24
            const float* src = X + (size_t)(row0 + r) * WIDTH + (size_t)h0 * 32 + g;
            v8h pk;
            #pragma unroll
            for (int j = 0; j < 8; ++j)
                pk[j] = (_Float16)src[j * 32];    // column 32*(h0+j)+g
            *(v8h*)(Xb + xoff(g, r, h0)) = pk;
        }
    }
    __syncthreads();

    for (int L = 0; L < DEPTH; ++L) {
        const bool last = (L == DEPTH - 1);

        // ================= phase 1: mix h (slices = g) =================
        {
            const unsigned short* m1 = mats + (size_t)(L * 2 + 0) * 32 * 1024;
            v8h aF[8];
            #pragma unroll
            for (int i = 0; i < 8; ++i)
                aF[i] = *(const v8h*)(Xb + xoff(oct * 8 + i, lw, q * 8));
            __syncthreads();                      // all reads landed before writes
            #pragma unroll
            for (int s = 0; s < 2; ++s) {
                const int gbase = oct * 8 + s * 4;
                #pragma unroll
                for (int nt = 0; nt < 2; ++nt) {
                    v4f C[4];
                    #pragma unroll
                    for (int gi = 0; gi < 4; ++gi) {
                        const v8h B = *(const v8h*)&m1[(size_t)(gbase + gi) * 1024
                                                       + nt * 512 + lane * 8];
                        C[gi] = __builtin_amdgcn_mfma_f32_16x16x32_f16(
                            aF[s * 4 + gi], B, (v4f){0.f, 0.f, 0.f, 0.f}, 0, 0, 0);
                    }
                    const int hout = nt * 16 + lw;
                    #pragma unroll
                    for (int r = 0; r < 4; ++r) {
                        v4h pk = { (_Float16)C[0][r], (_Float16)C[1][r],
                                   (_Float16)C[2][r], (_Float16)C[3][r] };
                        *(v4h*)(Xb + xoff(hout, q * 4 + r, gbase)) = pk;
                    }
                }
            }
            __syncthreads();
        }

        // ================= phase 2: mix g (slices = h), + activation ====
        {
            const unsigned short* m2 = mats + (size_t)(L * 2 + 1) * 32 * 1024;
            v8h aF[8];
            #pragma unroll
            for (int i = 0; i < 8; ++i)
                aF[i] = *(const v8h*)(Xb + xoff(oct * 8 + i, lw, q * 8));
            __syncthreads();
            #pragma unroll
            for (int s = 0; s < 2; ++s) {
                const int hbase = oct * 8 + s * 4;
                #pragma unroll
                for (int nt = 0; nt < 2; ++nt) {
                    v4f C[4];
                    #pragma unroll
                    for (int hi = 0; hi < 4; ++hi) {
                        const v8h B = *(const v8h*)&m2[(size_t)(hbase + hi) * 1024
                                                       + nt * 512 + lane * 8];
                        C[hi] = __builtin_amdgcn_mfma_f32_16x16x32_f16(
                            aF[s * 4 + hi], B, (v4f){0.f, 0.f, 0.f, 0.f}, 0, 0, 0);
                    }
                    const int gout = nt * 16 + lw;
                    if (!last) {
                        float4 ac[4];
                        #pragma unroll
                        for (int hi = 0; hi < 4; ++hi)
                            ac[hi] = actT[(size_t)L * WIDTH + (hbase + hi) * 32 + gout];
                        #pragma unroll
                        for (int r = 0; r < 4; ++r) {
                            v4h pk;
                            #pragma unroll
                            for (int hi = 0; hi < 4; ++hi) {
                                float u = fmaf(C[hi][r], ac[hi].x, -ac[hi].y);
                                u = fminf(1.0f, fmaxf(-1.0f, u));   // -> v_med3
                                const float u2 = u * u;
                                const float p5 = fmaf(u2, 0.375f, -1.25f);
                                const float p3 = fmaf(u2, p5, 1.875f);
                                pk[hi] = (_Float16)(u * p3 * ac[hi].z);
                            }
                            *(v4h*)(Xb + xoff(gout, q * 4 + r, hbase)) = pk;
                        }
                    } else {
                        #pragma unroll
                        for (int hi = 0; hi < 4; ++hi) {
                            #pragma unroll
                            for (int r = 0; r < 4; ++r)
                                out[(size_t)(row0 + q * 4 + r) * WIDTH
                                    + (hbase + hi) * 32 + gout] = C[hi][r];
                        }
                    }
                }
            }
            if (!last) __syncthreads();
        }
    }
}

extern "C" void kernel_launch(void* const* d_in, const int* in_sizes, int n_in,
                              void* d_out, int out_size, void* d_ws, size_t ws_size,
                              hipStream_t stream)
{
    const float* X     = (const float*)d_in[0];
    const float* bp    = (const float*)d_in[1];
    const float* bias  = (const float*)d_in[2];
    const float* slope = (const float*)d_in[3];
    const float* scale = (const float*)d_in[4];
    unsigned short* mats = (unsigned short*)d_ws;                    // 1 MB
    float4* actT = (float4*)((char*)d_ws + 512 * 1024 * 2);          // 112 KB

    hipLaunchKernelGGL(gen_mats, dim3(512), dim3(64), 0, stream, bp, mats);
    hipLaunchKernelGGL(fuse_act, dim3(((DEPTH - 1) * WIDTH + 255) / 256), dim3(256),
                       0, stream, bias, slope, scale, actT);
    hipLaunchKernelGGL(butterfly_net, dim3(BATCH / ROWS), dim3(256), 0, stream,
                       X, mats, actT, (float*)d_out);
}

// Round 4
// 767.888 us; speedup vs baseline: 1.7355x; 1.7355x over previous
//
#include <hip/hip_runtime.h>

#define WIDTH   1024
#define HALF_W  512
#define DEPTH   8
#define BDEPTH  10
#define BATCH   65536
#define ROWS    16          // batch rows per block

typedef _Float16 v8h __attribute__((ext_vector_type(8)));   // MFMA A/B frag (4 VGPR)
typedef _Float16 v4h __attribute__((ext_vector_type(4)));   // packed 4 x fp16 (8 B)
typedef float    v4f __attribute__((ext_vector_type(4)));   // MFMA C/D frag

static __device__ __forceinline__ unsigned short f2h(float x) {
    _Float16 h = (_Float16)x;                 // RNE, rel err <= 2^-11
    return __builtin_bit_cast(unsigned short, h);
}

// ---------------------------------------------------------------------------
// LDS layout: 32 slices x 16 rows x 32 fp16, slice stride 1024 B (32 KB total).
// Swizzle: byte ^= (((r>>1) ^ slice) & 7) << 4.
//   Bijective: XOR touches bits [6:4]; key depends on r>>1 (addr bits >=7)
//   and slice (bits >=10), both invariant under the XOR.
//   Conflict audit at quarter-wave granularity (16 lanes):
//     A-read  b128 (r=lw, k=q*8):  slot=((lw&1)<<2|q)^(lw>>1) -> 2 lanes/slot
//     T-write b64  (slice=nt*16+lw): slot=const^(lw&7)        -> 2 lanes/2banks
//     init   b128  (slice=g):        slot=const^(g&7)         -> 2 lanes/slot
//   All <=2-way: free (m136).
// ---------------------------------------------------------------------------
static __device__ __forceinline__ int xoff(int slice, int r, int k) {
    int b = (slice << 10) + (r << 6) + (k << 1);
    return b ^ ((((r >> 1) ^ slice) & 7) << 4);
}

// ---------------------------------------------------------------------------
// Setup: compose 5 butterfly steps into 32x32 matrices, write in B-frag order.
// ---------------------------------------------------------------------------
__global__ void gen_mats(const float* __restrict__ bp, unsigned short* __restrict__ mats)
{
    const int bid = blockIdx.x;
    const int grp = bid & 31;
    const int ph  = (bid >> 5) & 1;
    const int L   = bid >> 6;
    const int tid = threadIdx.x;

    __shared__ float M[2][32][32];

    for (int i = tid; i < 1024; i += 64)
        M[0][i >> 5][i & 31] = ((i >> 5) == (i & 31)) ? 1.0f : 0.0f;
    __syncthreads();

    int buf = 0;
    for (int s = 0; s < 5; ++s) {
        const int t = ph * 5 + s;
        const int stride = 1 << (4 - s);
        for (int idx = tid; idx < 512; idx += 64) {
            const int a  = idx >> 5;
            const int c  = idx & 31;
            const int lo = ((a & ~(stride - 1)) << 1) | (a & (stride - 1));
            const int hi = lo | stride;
            const int p_low = (ph == 0) ? ((lo << 5) | grp) : ((grp << 5) | lo);
            const int j = (((p_low << t) | (p_low >> (10 - t))) & 1023) & 511;
            const float theta = bp[L * (HALF_W * BDEPTH) + j * BDEPTH + t];
            float sn, cs;
            sincosf(theta, &sn, &cs);
            const float xl = M[buf][lo][c];
            const float xh = M[buf][hi][c];
            M[1 - buf][lo][c] =  cs * xl + sn * xh;
            M[1 - buf][hi][c] = -sn * xl + cs * xh;
        }
        buf = 1 - buf;
        __syncthreads();
    }

    unsigned short* out = mats + (size_t)bid * 1024;
    for (int i = tid; i < 1024; i += 64) {
        const int nt   = i >> 9;
        const int lane = (i >> 3) & 63;
        const int jj   = i & 7;
        const int n = nt * 16 + (lane & 15);
        const int k = (lane >> 4) * 8 + jj;
        out[i] = f2h(M[buf][n][k]);
    }
}

// ---------------------------------------------------------------------------
// Fuse activation constants: {slope/scale, bias/scale, scale, 0} per (L, p).
// ---------------------------------------------------------------------------
__global__ void fuse_act(const float* __restrict__ bias,
                         const float* __restrict__ slope,
                         const float* __restrict__ scale,
                         float4* __restrict__ actT)
{
    const int i = blockIdx.x * 256 + threadIdx.x;
    if (i < (DEPTH - 1) * WIDTH) {
        const float b = bias[i], s = slope[i], c = scale[i];
        const float r = 1.0f / c;
        actT[i] = make_float4(s * r, b * r, c, 0.0f);
    }
}

// ---------------------------------------------------------------------------
// Main: 16 rows per block, 256 threads (4 waves = 4 slice octets).
// Single 32 KB LDS buffer; phases transpose in place:
//   [stage 8 A-frags -> regs][BAR][MFMA + (act) + transposed write][BAR]
// VGPR-cap calibration (measured): cap = 256 / launch_bounds_arg2,
// independent of block size: (512,4)->64, (256,4)->64, (512,2)->128(124).
// Working set needs ~124 regs -> arg2 MUST be 2. At 124 regs the HW fits
// 4 waves/SIMD (occupancy halves at 128); 4-wave blocks + 32 KB LDS
// -> 4 independent blocks/CU = 16 waves, barriers uncoupled across blocks.
// ---------------------------------------------------------------------------
__global__ void __launch_bounds__(256, 2) butterfly_net(
    const float* __restrict__ X,
    const unsigned short* __restrict__ mats,
    const float4* __restrict__ actT,
    float* __restrict__ out)
{
    __shared__ unsigned char Xb[32 * 1024];   // 32 KB

    const int tid  = threadIdx.x;
    const int lane = tid & 63;
    const int oct  = tid >> 6;        // wave 0..3 = slice octet
    const int lw   = lane & 15;
    const int q    = lane >> 4;
    const int row0 = blockIdx.x * ROWS;

    // ---- initial staging: fp32 global -> fp16 LDS, layout (g, r, h)
    {
        const int g = tid & 31;
        const int m = tid >> 5;                   // 0..7
        #pragma unroll
        for (int it = 0; it < 8; ++it) {
            const int cmb = it * 8 + m;           // 0..63
            const int r   = cmb >> 2;             // 0..15
            const int h0  = (cmb & 3) * 8;        // 0,8,16,24
            const float* src = X + (size_t)(row0 + r) * WIDTH + (size_t)h0 * 32 + g;
            v8h pk;
            #pragma unroll
            for (int j = 0; j < 8; ++j)
                pk[j] = (_Float16)src[j * 32];    // column 32*(h0+j)+g
            *(v8h*)(Xb + xoff(g, r, h0)) = pk;
        }
    }
    __syncthreads();

    for (int L = 0; L < DEPTH; ++L) {
        const bool last = (L == DEPTH - 1);

        // ================= phase 1: mix h (slices = g) =================
        {
            const unsigned short* m1 = mats + (size_t)(L * 2 + 0) * 32 * 1024;
            v8h aF[8];
            #pragma unroll
            for (int i = 0; i < 8; ++i)
                aF[i] = *(const v8h*)(Xb + xoff(oct * 8 + i, lw, q * 8));
            __syncthreads();                      // all reads landed before writes
            #pragma unroll
            for (int s = 0; s < 2; ++s) {
                const int gbase = oct * 8 + s * 4;
                #pragma unroll
                for (int nt = 0; nt < 2; ++nt) {
                    v4f C[4];
                    #pragma unroll
                    for (int gi = 0; gi < 4; ++gi) {
                        const v8h B = *(const v8h*)&m1[(size_t)(gbase + gi) * 1024
                                                       + nt * 512 + lane * 8];
                        C[gi] = __builtin_amdgcn_mfma_f32_16x16x32_f16(
                            aF[s * 4 + gi], B, (v4f){0.f, 0.f, 0.f, 0.f}, 0, 0, 0);
                    }
                    const int hout = nt * 16 + lw;
                    #pragma unroll
                    for (int r = 0; r < 4; ++r) {
                        v4h pk = { (_Float16)C[0][r], (_Float16)C[1][r],
                                   (_Float16)C[2][r], (_Float16)C[3][r] };
                        *(v4h*)(Xb + xoff(hout, q * 4 + r, gbase)) = pk;
                    }
                }
            }
            __syncthreads();
        }

        // ================= phase 2: mix g (slices = h), + activation ====
        {
            const unsigned short* m2 = mats + (size_t)(L * 2 + 1) * 32 * 1024;
            v8h aF[8];
            #pragma unroll
            for (int i = 0; i < 8; ++i)
                aF[i] = *(const v8h*)(Xb + xoff(oct * 8 + i, lw, q * 8));
            __syncthreads();
            #pragma unroll
            for (int s = 0; s < 2; ++s) {
                const int hbase = oct * 8 + s * 4;
                #pragma unroll
                for (int nt = 0; nt < 2; ++nt) {
                    v4f C[4];
                    #pragma unroll
                    for (int hi = 0; hi < 4; ++hi) {
                        const v8h B = *(const v8h*)&m2[(size_t)(hbase + hi) * 1024
                                                       + nt * 512 + lane * 8];
                        C[hi] = __builtin_amdgcn_mfma_f32_16x16x32_f16(
                            aF[s * 4 + hi], B, (v4f){0.f, 0.f, 0.f, 0.f}, 0, 0, 0);
                    }
                    const int gout = nt * 16 + lw;
                    if (!last) {
                        float4 ac[4];
                        #pragma unroll
                        for (int hi = 0; hi < 4; ++hi)
                            ac[hi] = actT[(size_t)L * WIDTH + (hbase + hi) * 32 + gout];
                        #pragma unroll
                        for (int r = 0; r < 4; ++r) {
                            v4h pk;
                            #pragma unroll
                            for (int hi = 0; hi < 4; ++hi) {
                                float u = fmaf(C[hi][r], ac[hi].x, -ac[hi].y);
                                u = fminf(1.0f, fmaxf(-1.0f, u));   // -> v_med3
                                const float u2 = u * u;
                                const float p5 = fmaf(u2, 0.375f, -1.25f);
                                const float p3 = fmaf(u2, p5, 1.875f);
                                pk[hi] = (_Float16)(u * p3 * ac[hi].z);
                            }
                            *(v4h*)(Xb + xoff(gout, q * 4 + r, hbase)) = pk;
                        }
                    } else {
                        #pragma unroll
                        for (int hi = 0; hi < 4; ++hi) {
                            #pragma unroll
                            for (int r = 0; r < 4; ++r)
                                out[(size_t)(row0 + q * 4 + r) * WIDTH
                                    + (hbase + hi) * 32 + gout] = C[hi][r];
                        }
                    }
                }
            }
            if (!last) __syncthreads();
        }
    }
}

extern "C" void kernel_launch(void* const* d_in, const int* in_sizes, int n_in,
                              void* d_out, int out_size, void* d_ws, size_t ws_size,
                              hipStream_t stream)
{
    const float* X     = (const float*)d_in[0];
    const float* bp    = (const float*)d_in[1];
    const float* bias  = (const float*)d_in[2];
    const float* slope = (const float*)d_in[3];
    const float* scale = (const float*)d_in[4];
    unsigned short* mats = (unsigned short*)d_ws;                    // 1 MB
    float4* actT = (float4*)((char*)d_ws + 512 * 1024 * 2);          // 112 KB

    hipLaunchKernelGGL(gen_mats, dim3(512), dim3(64), 0, stream, bp, mats);
    hipLaunchKernelGGL(fuse_act, dim3(((DEPTH - 1) * WIDTH + 255) / 256), dim3(256),
                       0, stream, bias, slope, scale, actT);
    hipLaunchKernelGGL(butterfly_net, dim3(BATCH / ROWS), dim3(256), 0, stream,
                       X, mats, actT, (float*)d_out);
}

// Round 5
// 758.151 us; speedup vs baseline: 1.7578x; 1.0128x over previous
//
#include <hip/hip_runtime.h>

#define WIDTH   1024
#define HALF_W  512
#define DEPTH   8
#define BDEPTH  10
#define BATCH   65536
#define ROWS    16          // batch rows per block

typedef _Float16 v8h __attribute__((ext_vector_type(8)));   // MFMA A/B frag (4 VGPR)
typedef _Float16 v4h __attribute__((ext_vector_type(4)));   // packed 4 x fp16 (8 B)
typedef float    v4f __attribute__((ext_vector_type(4)));   // MFMA C/D frag

static __device__ __forceinline__ unsigned short f2h(float x) {
    _Float16 h = (_Float16)x;                 // RNE, rel err <= 2^-11
    return __builtin_bit_cast(unsigned short, h);
}

// ---------------------------------------------------------------------------
// LDS layout: 32 slices x 16 rows x 32 fp16, slice stride 1024 B (32 KB total).
// Swizzle: byte ^= (((r>>1) ^ slice) & 7) << 4.  Bijective (XOR bits [6:4],
// key from addr bits >=7).  Conflict audit at quarter-wave granularity,
// with 4-slice wave bases (slice base only rotates slots via slice&7):
//   A-read  b128 (slice=w4+i, r=lw, k=q*8): slot=((lw&1)<<2|q)^(lw>>1)^c
//       -> each of 8 slots hit by exactly 2 lanes -> 2-way, free (m136)
//   T-write b64  (slice=nt*16+lw, k=w4):    slot=c^(lw&7) -> 2-way, free
//   init  b128   (slice=g, r,h0 fixed):     slot=c^(g&7)  -> 2-way, free
// ---------------------------------------------------------------------------
static __device__ __forceinline__ int xoff(int slice, int r, int k) {
    int b = (slice << 10) + (r << 6) + (k << 1);
    return b ^ ((((r >> 1) ^ slice) & 7) << 4);
}

// ---------------------------------------------------------------------------
// Setup: compose 5 butterfly steps into 32x32 matrices, write in B-frag order.
// ---------------------------------------------------------------------------
__global__ void gen_mats(const float* __restrict__ bp, unsigned short* __restrict__ mats)
{
    const int bid = blockIdx.x;
    const int grp = bid & 31;
    const int ph  = (bid >> 5) & 1;
    const int L   = bid >> 6;
    const int tid = threadIdx.x;

    __shared__ float M[2][32][32];

    for (int i = tid; i < 1024; i += 64)
        M[0][i >> 5][i & 31] = ((i >> 5) == (i & 31)) ? 1.0f : 0.0f;
    __syncthreads();

    int buf = 0;
    for (int s = 0; s < 5; ++s) {
        const int t = ph * 5 + s;
        const int stride = 1 << (4 - s);
        for (int idx = tid; idx < 512; idx += 64) {
            const int a  = idx >> 5;
            const int c  = idx & 31;
            const int lo = ((a & ~(stride - 1)) << 1) | (a & (stride - 1));
            const int hi = lo | stride;
            const int p_low = (ph == 0) ? ((lo << 5) | grp) : ((grp << 5) | lo);
            const int j = (((p_low << t) | (p_low >> (10 - t))) & 1023) & 511;
            const float theta = bp[L * (HALF_W * BDEPTH) + j * BDEPTH + t];
            float sn, cs;
            sincosf(theta, &sn, &cs);
            const float xl = M[buf][lo][c];
            const float xh = M[buf][hi][c];
            M[1 - buf][lo][c] =  cs * xl + sn * xh;
            M[1 - buf][hi][c] = -sn * xl + cs * xh;
        }
        buf = 1 - buf;
        __syncthreads();
    }

    unsigned short* out = mats + (size_t)bid * 1024;
    for (int i = tid; i < 1024; i += 64) {
        const int nt   = i >> 9;
        const int lane = (i >> 3) & 63;
        const int jj   = i & 7;
        const int n = nt * 16 + (lane & 15);
        const int k = (lane >> 4) * 8 + jj;
        out[i] = f2h(M[buf][n][k]);
    }
}

// ---------------------------------------------------------------------------
// Fuse activation constants: {slope/scale, bias/scale, scale, 0} per (L, p).
// ---------------------------------------------------------------------------
__global__ void fuse_act(const float* __restrict__ bias,
                         const float* __restrict__ slope,
                         const float* __restrict__ scale,
                         float4* __restrict__ actT)
{
    const int i = blockIdx.x * 256 + threadIdx.x;
    if (i < (DEPTH - 1) * WIDTH) {
        const float b = bias[i], s = slope[i], c = scale[i];
        const float r = 1.0f / c;
        actT[i] = make_float4(s * r, b * r, c, 0.0f);
    }
}

// ---------------------------------------------------------------------------
// Main: 16 rows per block, 512 threads = 8 waves x 4 slices each.
// Single 32 KB LDS buffer; phases transpose in place:
//   [stage 4 A-frags -> regs][BAR][8 MFMA + (act) + transposed write][BAR]
// R4 post-mortem: at 8 slices/wave the working set pinned the 128-VGPR cap
// and overflowed into AGPRs -> total regs > 128 -> 2 waves/SIMD -> 23% occ.
// Halving slices/wave cuts aF staging 32->16 regs and B-frag pressure,
// targeting ~100 total regs -> 4 waves/SIMD -> 2 blocks x 8 waves = 16
// waves/CU (50%). LDS 2 x 32 KB fits. Tripwire: VGPR_Count pinned at 128
// again means AGPR overflow returned.
// __launch_bounds__ cap calibration (measured): cap = 256/arg2, independent
// of block size: (512,4)->64, (256,4)->64, (512,2)->128, (256,2)->128.
// ---------------------------------------------------------------------------
__global__ void __launch_bounds__(512, 2) butterfly_net(
    const float* __restrict__ X,
    const unsigned short* __restrict__ mats,
    const float4* __restrict__ actT,
    float* __restrict__ out)
{
    __shared__ unsigned char Xb[32 * 1024];   // 32 KB

    const int tid  = threadIdx.x;
    const int lane = tid & 63;
    const int w4   = (tid >> 6) * 4;  // wave's 4-slice base (0,4,...,28)
    const int lw   = lane & 15;
    const int q    = lane >> 4;
    const int row0 = blockIdx.x * ROWS;

    // ---- initial staging: fp32 global -> fp16 LDS, layout (g, r, h)
    {
        const int g = tid & 31;
        const int m = tid >> 5;                   // 0..15
        #pragma unroll
        for (int it = 0; it < 4; ++it) {
            const int cmb = it * 16 + m;          // 0..63
            const int r   = cmb >> 2;             // 0..15
            const int h0  = (cmb & 3) * 8;        // 0,8,16,24
            const float* src = X + (size_t)(row0 + r) * WIDTH + (size_t)h0 * 32 + g;
            v8h pk;
            #pragma unroll
            for (int j = 0; j < 8; ++j)
                pk[j] = (_Float16)src[j * 32];    // column 32*(h0+j)+g
            *(v8h*)(Xb + xoff(g, r, h0)) = pk;
        }
    }
    __syncthreads();

    for (int L = 0; L < DEPTH; ++L) {
        const bool last = (L == DEPTH - 1);

        // ================= phase 1: mix h (slices = g) =================
        {
            const unsigned short* m1 = mats + (size_t)(L * 2 + 0) * 32 * 1024;
            v8h aF[4];
            #pragma unroll
            for (int i = 0; i < 4; ++i)
                aF[i] = *(const v8h*)(Xb + xoff(w4 + i, lw, q * 8));
            __syncthreads();                      // all reads landed before writes
            #pragma unroll
            for (int nt = 0; nt < 2; ++nt) {
                v4f C[4];
                #pragma unroll
                for (int gi = 0; gi < 4; ++gi) {
                    const v8h B = *(const v8h*)&m1[(size_t)(w4 + gi) * 1024
                                                   + nt * 512 + lane * 8];
                    C[gi] = __builtin_amdgcn_mfma_f32_16x16x32_f16(
                        aF[gi], B, (v4f){0.f, 0.f, 0.f, 0.f}, 0, 0, 0);
                }
                const int hout = nt * 16 + lw;
                #pragma unroll
                for (int r = 0; r < 4; ++r) {
                    v4h pk = { (_Float16)C[0][r], (_Float16)C[1][r],
                               (_Float16)C[2][r], (_Float16)C[3][r] };
                    *(v4h*)(Xb + xoff(hout, q * 4 + r, w4)) = pk;
                }
            }
            __syncthreads();
        }

        // ================= phase 2: mix g (slices = h), + activation ====
        {
            const unsigned short* m2 = mats + (size_t)(L * 2 + 1) * 32 * 1024;
            v8h aF[4];
            #pragma unroll
            for (int i = 0; i < 4; ++i)
                aF[i] = *(const v8h*)(Xb + xoff(w4 + i, lw, q * 8));
            __syncthreads();
            #pragma unroll
            for (int nt = 0; nt < 2; ++nt) {
                v4f C[4];
                #pragma unroll
                for (int hi = 0; hi < 4; ++hi) {
                    const v8h B = *(const v8h*)&m2[(size_t)(w4 + hi) * 1024
                                                   + nt * 512 + lane * 8];
                    C[hi] = __builtin_amdgcn_mfma_f32_16x16x32_f16(
                        aF[hi], B, (v4f){0.f, 0.f, 0.f, 0.f}, 0, 0, 0);
                }
                const int gout = nt * 16 + lw;
                if (!last) {
                    float4 ac[4];
                    #pragma unroll
                    for (int hi = 0; hi < 4; ++hi)
                        ac[hi] = actT[(size_t)L * WIDTH + (w4 + hi) * 32 + gout];
                    #pragma unroll
                    for (int r = 0; r < 4; ++r) {
                        v4h pk;
                        #pragma unroll
                        for (int hi = 0; hi < 4; ++hi) {
                            float u = fmaf(C[hi][r], ac[hi].x, -ac[hi].y);
                            u = fminf(1.0f, fmaxf(-1.0f, u));   // -> v_med3
                            const float u2 = u * u;
                            const float p5 = fmaf(u2, 0.375f, -1.25f);
                            const float p3 = fmaf(u2, p5, 1.875f);
                            pk[hi] = (_Float16)(u * p3 * ac[hi].z);
                        }
                        *(v4h*)(Xb + xoff(gout, q * 4 + r, w4)) = pk;
                    }
                } else {
                    #pragma unroll
                    for (int hi = 0; hi < 4; ++hi) {
                        #pragma unroll
                        for (int r = 0; r < 4; ++r)
                            out[(size_t)(row0 + q * 4 + r) * WIDTH
                                + (w4 + hi) * 32 + gout] = C[hi][r];
                    }
                }
            }
            if (!last) __syncthreads();
        }
    }
}

extern "C" void kernel_launch(void* const* d_in, const int* in_sizes, int n_in,
                              void* d_out, int out_size, void* d_ws, size_t ws_size,
                              hipStream_t stream)
{
    const float* X     = (const float*)d_in[0];
    const float* bp    = (const float*)d_in[1];
    const float* bias  = (const float*)d_in[2];
    const float* slope = (const float*)d_in[3];
    const float* scale = (const float*)d_in[4];
    unsigned short* mats = (unsigned short*)d_ws;                    // 1 MB
    float4* actT = (float4*)((char*)d_ws + 512 * 1024 * 2);          // 112 KB

    hipLaunchKernelGGL(gen_mats, dim3(512), dim3(64), 0, stream, bp, mats);
    hipLaunchKernelGGL(fuse_act, dim3(((DEPTH - 1) * WIDTH + 255) / 256), dim3(256),
                       0, stream, bias, slope, scale, actT);
    hipLaunchKernelGGL(butterfly_net, dim3(BATCH / ROWS), dim3(512), 0, stream,
                       X, mats, actT, (float*)d_out);
}